// Round 1
// baseline (187.357 us; speedup 1.0000x reference)
//
#include <hip/hip_runtime.h>
#include <math.h>

// CapsuleLayer routing collapses (verified R1/R2, absmax 0.0):
//   out[b,j,d] = squash_d( (1/N) * sum_{n,i} x[b,n,i] * W[n,i,d] )  for all j.
// R4: fuse K1(reduce)+K2(combine+write) into ONE dispatch. The timed graph is
// dominated by harness re-poison fills (256 MiB ws fill = 40.8us @82% HBM —
// top-5 dispatches are all fillBufferAligned); our only remaining lever is
// dispatch count + the K1->K2 full-grid drain. Cross-block sync via
// agent-scope partial stores + MAGIC flag + spin:
//   - co-residency guaranteed: 1024 blocks, __launch_bounds__(256,4) caps
//     VGPR<=128 -> >=4 blocks/CU -> capacity 1024; every block flags BEFORE
//     spinning, so progress is unconditional.
//   - poison-safe: flags checked against a non-repeated-byte MAGIC; a stale
//     MAGIC replay would read byte-identical partials (same inputs,
//     deterministic FP), so the result is unchanged either way.
// Phase-1 math and all FP association orders are identical to the R3 pair
// (9-iter loop, shfl butterfly, (a+b)+(c+d) wave combine, sequential 16-slice
// combine) -> bitwise-identical output.

#define BATCH 64
#define NCAPS 1152   // per batch: 9216 (n,i) pairs

#define FLAG_MAGIC 0x5CA1AB1Eu

// grid = 64 b x 16 slices, block = 256.
// slice s covers pairs [s*576, (s+1)*576). thread t: dg = t&3 (4 out dims),
// stripe = t>>2 (64 stripes). Per k-iter a wave reads 64 consecutive float4
// of W (1 KB contiguous); x scalar broadcasts across the 4 dg-lanes.
__global__ __launch_bounds__(256, 4) void caps_fused(
    const float* __restrict__ x, const float* __restrict__ W,
    float* __restrict__ out,
    float* __restrict__ wsPart,          // [B][16 slices][16 dims] = 64 KB
    unsigned* __restrict__ wsFlag)       // [B][16 slices] = 4 KB
{
    const int b = blockIdx.x >> 4;
    const int s = blockIdx.x & 15;
    const int t = threadIdx.x;
    const int dg = t & 3;
    const int stripe = t >> 2;

    // ---- phase 1: partial reduction (identical to R3 K1) ----
    const float*  xb = x + (size_t)b * 9216 + s * 576;
    const float4* W4 = (const float4*)W + (size_t)s * 2304 + dg;

    float4 acc = make_float4(0.f, 0.f, 0.f, 0.f);
#pragma unroll
    for (int k = 0; k < 9; ++k) {
        const int p = k * 64 + stripe;
        const float  xs = xb[p];
        const float4 w  = W4[4 * p];
        acc.x += xs * w.x; acc.y += xs * w.y;
        acc.z += xs * w.z; acc.w += xs * w.w;
    }

    // reduce over the 16 stripes within each wave (lane bits 2..5), in-register
#pragma unroll
    for (int m = 4; m <= 32; m <<= 1) {
        acc.x += __shfl_xor(acc.x, m, 64);
        acc.y += __shfl_xor(acc.y, m, 64);
        acc.z += __shfl_xor(acc.z, m, 64);
        acc.w += __shfl_xor(acc.w, m, 64);
    }

    __shared__ float4 wred[16];          // [wave][dg]
    __shared__ float  ubar[16];
    const int wave = t >> 6;
    const int lane = t & 63;
    if (lane < 4) wred[wave * 4 + dg] = acc;   // lane == dg for lanes 0..3
    __syncthreads();

    if (t < 4) {                         // t == dg; dims [4t, 4t+4)
        const float4 a = wred[t],     b4 = wred[4 + t];
        const float4 c = wred[8 + t], d4 = wred[12 + t];
        float4 r;
        r.x = (a.x + b4.x) + (c.x + d4.x);
        r.y = (a.y + b4.y) + (c.y + d4.y);
        r.z = (a.z + b4.z) + (c.z + d4.z);
        r.w = (a.w + b4.w) + (c.w + d4.w);
        float* dst = wsPart + (((size_t)b * 16 + s) * 16) + t * 4;
        __hip_atomic_store(dst + 0, r.x, __ATOMIC_RELAXED, __HIP_MEMORY_SCOPE_AGENT);
        __hip_atomic_store(dst + 1, r.y, __ATOMIC_RELAXED, __HIP_MEMORY_SCOPE_AGENT);
        __hip_atomic_store(dst + 2, r.z, __ATOMIC_RELAXED, __HIP_MEMORY_SCOPE_AGENT);
        __hip_atomic_store(dst + 3, r.w, __ATOMIC_RELAXED, __HIP_MEMORY_SCOPE_AGENT);
    }
    __syncthreads();                     // partial stores happen-before flag

    // ---- publish + spin for this batch's 16 slices ----
    if (t == 0) {
        __hip_atomic_store(&wsFlag[b * 16 + s], FLAG_MAGIC,
                           __ATOMIC_RELEASE, __HIP_MEMORY_SCOPE_AGENT);
        const unsigned* fl = wsFlag + b * 16;
        for (int i = 0; i < 16; ++i) {
            while (__hip_atomic_load(&fl[i], __ATOMIC_ACQUIRE,
                                     __HIP_MEMORY_SCOPE_AGENT) != FLAG_MAGIC)
                __builtin_amdgcn_s_sleep(2);
        }
    }
    __syncthreads();                     // flag acquire happens-before reads

    // ---- phase 2: combine (identical association to R3 K2) + squash ----
    if (t < 16) {                        // dim t; sequential over slices s=0..15
        const float* pp = wsPart + (size_t)b * 256 + t;
        float g = 0.f;
#pragma unroll
        for (int i = 0; i < 16; ++i)
            g += __hip_atomic_load(pp + i * 16, __ATOMIC_RELAXED,
                                   __HIP_MEMORY_SCOPE_AGENT);
        ubar[t] = g * (1.0f / (float)NCAPS);
    }
    __syncthreads();

    float sq = 0.f;
#pragma unroll
    for (int d = 0; d < 16; ++d) sq += ubar[d] * ubar[d];
    const float scale = sq / (1.0f + sq) / sqrtf(sq + 1e-8f);

    // ---- broadcast write: this block covers 72 rows = 288 float4 ----
    const float4 v = make_float4(scale * ubar[dg * 4 + 0],
                                 scale * ubar[dg * 4 + 1],
                                 scale * ubar[dg * 4 + 2],
                                 scale * ubar[dg * 4 + 3]);
    float4* outp = (float4*)out + (size_t)b * 4608 + (size_t)s * 288;
    outp[t] = v;                         // (t+256)&3 == t&3, so v is reusable
    if (t < 32) outp[256 + t] = v;
}

extern "C" void kernel_launch(void* const* d_in, const int* in_sizes, int n_in,
                              void* d_out, int out_size, void* d_ws, size_t ws_size,
                              hipStream_t stream) {
    const float* x = (const float*)d_in[0];
    const float* W = (const float*)d_in[1];
    float* out     = (float*)d_out;
    float* wsPart  = (float*)d_ws;                          // 64 KB
    unsigned* wsFlag = (unsigned*)((char*)d_ws + 65536);    // 4 KB

    caps_fused<<<BATCH * 16, 256, 0, stream>>>(x, W, out, wsPart, wsFlag);
}

// Round 2
// 60.222 us; speedup vs baseline: 3.1111x; 3.1111x over previous
//
#include <hip/hip_runtime.h>
#include <math.h>

// CapsuleLayer routing collapses (verified R1/R2, absmax 0.0):
//   out[b,j,d] = squash_d( (1/N) * sum_{n,i} x[b,n,i] * W[n,i,d] )  for all j.
// R3 (this version, 60.7us): two-kernel split, verified best.
// R4 POST-MORTEM (reverted): fusing K1+K2 into one dispatch with agent-scope
// flag/spin sync regressed 60.7 -> 187us. The fused kernel ran 137us at
// VALUBusy 0.8% / HBM 0.6%: pure idle spin. Cause: per-XCD L2s are not
// cross-coherent on gfx950, so each agent-scope release store = L2 writeback
// and each acquire spin-load = L2 invalidate; the harness's 256 MiB ws-poison
// fill (40.8us @82% HBM, serial in the timed graph) leaves L2 fully dirty, so
// 1024 blocks' release/acquire traffic thrashes L2 for ~330K cycles.
// Cross-block coherence costs ~30x the 2-4us of dispatch overhead it saves.
// Timed-region budget: ~40.8us harness ws fill + ~10-15us harness reset
// memsets/graph gaps + ~4us our two kernels. This is the floor we control.

#define BATCH 64
#define NCAPS 1152   // per batch: 9216 (n,i) pairs; W = 9216 float4 groups

// ---- K1: partial reduction. grid = 64 b x 16 slices, block = 256 ----
// slice s covers pairs [s*576, (s+1)*576). thread t: dg = t&3 (4 out dims),
// stripe = t>>2 (64 stripes). Per k-iter a wave reads 64 consecutive float4
// of W (1 KB contiguous); x scalar broadcasts across the 4 dg-lanes.
__global__ __launch_bounds__(256) void caps_reduce(
    const float* __restrict__ x, const float* __restrict__ W,
    float* __restrict__ ws)   // ws: [B][16][16] floats = 64 KB
{
    const int b = blockIdx.x >> 4;
    const int s = blockIdx.x & 15;
    const int t = threadIdx.x;
    const int dg = t & 3;
    const int stripe = t >> 2;

    const float*  xb = x + (size_t)b * 9216 + s * 576;
    const float4* W4 = (const float4*)W + (size_t)s * 2304 + dg;

    float4 acc = make_float4(0.f, 0.f, 0.f, 0.f);
#pragma unroll
    for (int k = 0; k < 9; ++k) {
        const int p = k * 64 + stripe;
        const float  xs = xb[p];
        const float4 w  = W4[4 * p];
        acc.x += xs * w.x; acc.y += xs * w.y;
        acc.z += xs * w.z; acc.w += xs * w.w;
    }

    // reduce over the 16 stripes within each wave (lane bits 2..5), in-register
#pragma unroll
    for (int m = 4; m <= 32; m <<= 1) {
        acc.x += __shfl_xor(acc.x, m, 64);
        acc.y += __shfl_xor(acc.y, m, 64);
        acc.z += __shfl_xor(acc.z, m, 64);
        acc.w += __shfl_xor(acc.w, m, 64);
    }

    __shared__ float4 wred[16];          // [wave][dg]
    const int wave = t >> 6;
    const int lane = t & 63;
    if (lane < 4) wred[wave * 4 + dg] = acc;   // lane == dg for lanes 0..3
    __syncthreads();

    if (t < 4) {                         // t == dg
        const float4 a = wred[t],     b4 = wred[4 + t];
        const float4 c = wred[8 + t], d4 = wred[12 + t];
        float4 r;
        r.x = (a.x + b4.x) + (c.x + d4.x);
        r.y = (a.y + b4.y) + (c.y + d4.y);
        r.z = (a.z + b4.z) + (c.z + d4.z);
        r.w = (a.w + b4.w) + (c.w + d4.w);
        ((float4*)ws)[b * 64 + s * 4 + t] = r;
    }
}

// ---- K2: combine partials + squash + broadcast write ----
// grid = 64*18 = 1152, block = 256: exactly one coalesced float4 store/thread.
__global__ __launch_bounds__(256) void caps_write(
    const float* __restrict__ ws, float* __restrict__ out)
{
    const int blk = blockIdx.x;
    const int b   = blk / 18;
    const int t   = threadIdx.x;

    __shared__ float4 sh[64];
    __shared__ float  ubar[16];
    if (t < 64) sh[t] = ((const float4*)ws)[b * 64 + t];
    __syncthreads();

    if (t < 4) {                         // t == dg
        float4 r = make_float4(0.f, 0.f, 0.f, 0.f);
#pragma unroll
        for (int s = 0; s < 16; ++s) {
            const float4 v = sh[s * 4 + t];
            r.x += v.x; r.y += v.y; r.z += v.z; r.w += v.w;
        }
        const float inv = 1.0f / (float)NCAPS;
        ubar[t * 4 + 0] = r.x * inv; ubar[t * 4 + 1] = r.y * inv;
        ubar[t * 4 + 2] = r.z * inv; ubar[t * 4 + 3] = r.w * inv;
    }
    __syncthreads();

    float sq = 0.f;
#pragma unroll
    for (int d = 0; d < 16; ++d) sq += ubar[d] * ubar[d];
    const float scale = sq / (1.0f + sq) / sqrtf(sq + 1e-8f);

    const int dg = t & 3;
    const float4 v = make_float4(scale * ubar[dg * 4 + 0],
                                 scale * ubar[dg * 4 + 1],
                                 scale * ubar[dg * 4 + 2],
                                 scale * ubar[dg * 4 + 3]);
    ((float4*)out)[(size_t)blk * 256 + t] = v;
}

extern "C" void kernel_launch(void* const* d_in, const int* in_sizes, int n_in,
                              void* d_out, int out_size, void* d_ws, size_t ws_size,
                              hipStream_t stream) {
    const float* x = (const float*)d_in[0];
    const float* W = (const float*)d_in[1];
    float* out     = (float*)d_out;
    float* ws      = (float*)d_ws;     // 64 KB used

    caps_reduce<<<BATCH * 16, 256, 0, stream>>>(x, W, ws);
    caps_write <<<BATCH * 18, 256, 0, stream>>>(ws, out);
}